// Round 3
// baseline (5507.863 us; speedup 1.0000x reference)
//
#include <hip/hip_runtime.h>
#include <hip/hip_bf16.h>
#include <math.h>

#define BTOT   16384
#define NLAYER 24
#define HID    192
#define NHALF  6
#define NDIN   12
#define NBASE  66
#define EPSP   1e-3f

// ---------------- LDS layout (floats) for flow_kernel ----------------
// All [row][e] arrays use stride 64 (2-way bank aliasing = free on CDNA4).
#define O_H1   0        // 192*64  h1 values (reused as G_h2 buffer in VJP)
#define O_R    12288    // 6*12*64 cotangent rows R
#define O_PP   16896    // 8*12*64 prm partial sums (overlaid with sGZ 8*6*64)
#define O_GP   23040    // 12*64   g_prm
#define O_GP2  23808    // 6*64    saved r2
#define O_ES   24192    // 6*64    exp(s)
#define O_TF   24576    // 6*64    tv*fac  (tv = z2*e^s = y1-shift, fac = 1-(s/2)^2)
#define O_SV   24960    // 6*64    s values
#define O_Z    25344    // 12*64   z state
#define O_LD   26112    // 64      logdet accumulator
#define O_RED  26176    // 8       block reduction scratch
#define SMEM_FLOATS 26184
#define SMEM_BYTES  (SMEM_FLOATS*4)

// ---------------------------------------------------------------------
// flow_kernel: per block = 64 batch elements (lane = element), 8 waves.
// Wave w owns hidden-unit rows [24w, 24w+24). Layers processed 23..0:
// inverse coupling step fused with the VJP of the corresponding forward
// layer (the inverse step reconstructs exactly the forward activations).
// z and Jp are passed to kl_kernel IN PLACE through the y / J_p input
// buffers (harness restores inputs from pristine copies every launch).
__global__ __launch_bounds__(512) void flow_kernel(
    float* __restrict__ yz,       // in: y (B,12); out: z (B,12)
    float* __restrict__ jp,       // in: J_p (B,6,12); out: pullback Jp
    const float* __restrict__ W1, const float* __restrict__ b1,
    const float* __restrict__ W2, const float* __restrict__ b2,
    const float* __restrict__ W3, const float* __restrict__ b3,
    float* __restrict__ ws_sum, float* __restrict__ out_lp) {
  extern __shared__ float sm[];
  float* sH1  = sm + O_H1;   // also used as sG (G_h2) during VJP
  float* sR   = sm + O_R;
  float* sPP  = sm + O_PP;   // also used as sGZ during VJP
  float* sGP  = sm + O_GP;
  float* sGP2 = sm + O_GP2;
  float* sES  = sm + O_ES;
  float* sTF  = sm + O_TF;
  float* sSV  = sm + O_SV;
  float* sZ   = sm + O_Z;
  float* sLD  = sm + O_LD;
  float* sRed = sm + O_RED;
  float* sG   = sH1;
  float* sGZ  = sPP;

  const int tid  = threadIdx.x;
  const int lane = tid & 63;
  const int e    = lane;                                     // element in block
  const int w    = __builtin_amdgcn_readfirstlane(tid >> 6); // wave id 0..7
  const int jb   = 24 * w;                                   // row-slab base
  const int blk  = blockIdx.x;
  const int elem = blk * 64 + e;

  // ---- init state ----
  if (w == 0) {
    #pragma unroll
    for (int i = 0; i < 12; ++i) sZ[i * 64 + e] = yz[elem * 12 + i];
    sLD[e] = 0.f;
  }
  for (int idx = tid; idx < 72 * 64; idx += 512) {
    int rt = idx >> 6, ee = idx & 63;
    sR[idx] = jp[(blk * 64 + ee) * 72 + rt];
  }
  __syncthreads();

  unsigned m1 = 0, m2 = 0;  // relu masks for this wave's 24 rows

  for (int l = NLAYER - 1; l >= 0; --l) {
    const float* W1l = W1 + l * HID * NHALF;
    const float* b1l = b1 + l * HID;
    const float* W2l = W2 + l * HID * HID;
    const float* b2l = b2 + l * HID;
    const float* W3l = W3 + l * NDIN * HID;
    const float* b3l = b3 + l * NDIN;

    // ---- F1: h1 = relu(W1 z1 + b1), z1 = swapped half = z[6:12] ----
    m1 = 0;
    {
      float z1v[6];
      #pragma unroll
      for (int i = 0; i < 6; ++i) z1v[i] = sZ[(6 + i) * 64 + e];
      #pragma unroll
      for (int jj = 0; jj < 24; ++jj) {
        int j = jb + jj;
        float acc = b1l[j];
        #pragma unroll
        for (int i = 0; i < 6; ++i) acc = fmaf(W1l[j * 6 + i], z1v[i], acc);
        m1 |= (acc > 0.f ? 1u : 0u) << jj;
        sH1[j * 64 + e] = fmaxf(acc, 0.f);
      }
    }
    __syncthreads();

    // ---- F2: h2 = relu(W2 h1 + b2); prm partials via W3 ----
    {
      float acc[24];
      #pragma unroll
      for (int jj = 0; jj < 24; ++jj) acc[jj] = b2l[jb + jj];
      for (int k = 0; k < HID; ++k) {
        float h1k = sH1[k * 64 + e];
        #pragma unroll
        for (int jj = 0; jj < 24; ++jj)
          acc[jj] = fmaf(W2l[(jb + jj) * HID + k], h1k, acc[jj]);  // W2[j,k], uniform
      }
      float h2v[24];
      m2 = 0;
      #pragma unroll
      for (int jj = 0; jj < 24; ++jj) {
        m2 |= (acc[jj] > 0.f ? 1u : 0u) << jj;
        h2v[jj] = fmaxf(acc[jj], 0.f);
      }
      #pragma unroll
      for (int t = 0; t < 12; ++t) {
        const float* w3r = W3l + t * HID + jb;
        float pp = 0.f;
        #pragma unroll
        for (int jj = 0; jj < 24; ++jj) pp = fmaf(w3r[jj], h2v[jj], pp);
        sPP[(w * 12 + t) * 64 + e] = pp;
      }
    }
    __syncthreads();

    // ---- U: finish prm, coupling update, stash VJP aux ----
    if (tid < 384) {
      int i = w;  // 0..5
      float shift = b3l[2 * i], sraw = b3l[2 * i + 1];
      #pragma unroll
      for (int ww = 0; ww < 8; ++ww) {
        shift += sPP[(ww * 12 + 2 * i) * 64 + e];
        sraw  += sPP[(ww * 12 + 2 * i + 1) * 64 + e];
      }
      float s   = 2.f * tanhf(0.5f * sraw);
      float es  = expf(s);
      float en  = expf(-s);
      float fac = 1.f - 0.25f * s * s;
      float z2o = sZ[i * 64 + e];        // pre-update first half
      float z1o = sZ[(6 + i) * 64 + e];
      float tv  = z2o - shift;           // = z2_fwd * e^s
      sZ[i * 64 + e]       = z1o;        // new z1
      sZ[(6 + i) * 64 + e] = tv * en;    // new z2
      sES[i * 64 + e] = es;
      sTF[i * 64 + e] = tv * fac;
      sSV[i * 64 + e] = s;
    }
    __syncthreads();

    if (tid < 64) {
      float ss = 0.f;
      #pragma unroll
      for (int i = 0; i < 6; ++i) ss += sSV[i * 64 + tid];
      sLD[tid] -= ss;
    }

    // ---- VJP: pull 6 cotangent rows through this forward layer ----
    for (int r = 0; r < 6; ++r) {
      // V1: g_prm; update second-half cotangent in place (save r2 first)
      if (tid < 384) {
        int i = w;
        float r1 = sR[(r * 12 + i) * 64 + e];
        float r2 = sR[(r * 12 + 6 + i) * 64 + e];
        sGP[(2 * i) * 64 + e]     = r1;                    // g_shift
        sGP[(2 * i + 1) * 64 + e] = r1 * sTF[i * 64 + e];  // g_sraw
        sGP2[i * 64 + e] = r2;
        sR[(r * 12 + 6 + i) * 64 + e] = r1 * sES[i * 64 + e];  // g_z2
      }
      __syncthreads();

      // V2: G_h2 = mask2 .* (W3^T g_prm) for this wave's rows
      {
        float gp[12];
        #pragma unroll
        for (int t = 0; t < 12; ++t) gp[t] = sGP[t * 64 + e];
        float g[24];
        #pragma unroll
        for (int jj = 0; jj < 24; ++jj) g[jj] = 0.f;
        #pragma unroll
        for (int t = 0; t < 12; ++t) {
          const float* w3r = W3l + t * HID + jb;
          #pragma unroll
          for (int jj = 0; jj < 24; ++jj) g[jj] = fmaf(w3r[jj], gp[t], g[jj]);
        }
        #pragma unroll
        for (int jj = 0; jj < 24; ++jj)
          sG[(jb + jj) * 64 + e] = ((m2 >> jj) & 1) ? g[jj] : 0.f;
      }
      __syncthreads();

      // V3+V4: G_h1 = mask1 .* (W2^T G_h2); g_z1 partial = W1^T G_h1
      {
        float acc[24];
        #pragma unroll
        for (int kk = 0; kk < 24; ++kk) acc[kk] = 0.f;
        for (int j = 0; j < HID; ++j) {
          float gj = sG[j * 64 + e];
          const float* w2r = W2l + j * HID + jb;  // W2[j, jb+kk], uniform
          #pragma unroll
          for (int kk = 0; kk < 24; ++kk) acc[kk] = fmaf(w2r[kk], gj, acc[kk]);
        }
        #pragma unroll
        for (int kk = 0; kk < 24; ++kk)
          if (!((m1 >> kk) & 1)) acc[kk] = 0.f;
        float pz[6] = {0.f, 0.f, 0.f, 0.f, 0.f, 0.f};
        #pragma unroll
        for (int kk = 0; kk < 24; ++kk) {
          const float* w1r = W1l + (jb + kk) * 6;
          #pragma unroll
          for (int i = 0; i < 6; ++i) pz[i] = fmaf(w1r[i], acc[kk], pz[i]);
        }
        #pragma unroll
        for (int i = 0; i < 6; ++i) sGZ[(w * 6 + i) * 64 + e] = pz[i];
      }
      __syncthreads();

      // V5: g_z1 = r2 + sum of partials -> first-half cotangent
      if (tid < 384) {
        int i = w;
        float gz = sGP2[i * 64 + e];
        #pragma unroll
        for (int ww = 0; ww < 8; ++ww) gz += sGZ[(ww * 6 + i) * 64 + e];
        sR[(r * 12 + i) * 64 + e] = gz;
      }
      __syncthreads();
    }
  }

  // ---- epilogue ----
  if (tid == 0) sRed[0] = 0.f;
  __syncthreads();

  if (w == 0) {
    float zsq = 0.f;
    #pragma unroll
    for (int i = 0; i < 12; ++i) {
      float zi = sZ[i * 64 + e];
      zsq = fmaf(zi, zi, zsq);
      yz[elem * 12 + i] = zi;            // write z back into the y buffer
    }
    float lp = sLD[e] - 11.027262398456072f - 0.5f * zsq;
    out_lp[elem] = lp;                   // fp32 output
  }

  float part = 0.f;
  for (int idx = tid; idx < 72 * 64; idx += 512) {
    int rt = idx >> 6, ee = idx & 63;
    float v = sR[idx];
    jp[(blk * 64 + ee) * 72 + rt] = v;   // write Jp back into the J_p buffer
    part = fmaf(v, v, part);
  }
  #pragma unroll
  for (int off = 32; off > 0; off >>= 1) part += __shfl_down(part, off, 64);
  if (lane == 0) atomicAdd(&sRed[0], part);
  __syncthreads();
  if (tid == 0) atomicAdd(ws_sum, sRed[0]);
}

// ---------------------------------------------------------------------
// kl_kernel: one thread per element; everything in registers.
// A = Wsym - Wsym^T formed on the fly (wave-uniform scalar loads, cached).
__global__ __launch_bounds__(256) void kl_kernel(
    const float* __restrict__ zin, const float* __restrict__ jpin,
    const float* __restrict__ Wsym, const float* __restrict__ lvd,
    const float* __restrict__ ws_sum, float* __restrict__ out_kl) {
  int elem = blockIdx.x * 256 + threadIdx.x;
  float z[12];
  #pragma unroll
  for (int i = 0; i < 12; ++i) z[i] = zin[elem * 12 + i];
  float scale = 1.0f / sqrtf(ws_sum[0]);
  float Jp[6][12];
  #pragma unroll
  for (int n = 0; n < 6; ++n)
    #pragma unroll
    for (int j = 0; j < 12; ++j)
      Jp[n][j] = jpin[elem * 72 + n * 12 + j] * scale;

  float Sq[78];
  #pragma unroll
  for (int i = 0; i < 78; ++i) Sq[i] = 0.f;
  float tq = 0.f, tpq = 0.f;

  for (int m = 0; m < NBASE; ++m) {
    const float* Wm = Wsym + m * 144;
    float jq[12];
    #pragma unroll
    for (int j = 0; j < 12; ++j) {
      float acc = 0.f;
      #pragma unroll
      for (int i = 0; i < 12; ++i)
        acc = fmaf(Wm[j * 12 + i] - Wm[i * 12 + j], z[i], acc);
      jq[j] = acc;
    }
    #pragma unroll
    for (int i = 0; i < 12; ++i) {
      tq = fmaf(jq[i], jq[i], tq);
      #pragma unroll
      for (int j = 0; j <= i; ++j)
        Sq[i * (i + 1) / 2 + j] = fmaf(jq[i], jq[j], Sq[i * (i + 1) / 2 + j]);
    }
    #pragma unroll
    for (int n = 0; n < 6; ++n) {
      float d = 0.f;
      #pragma unroll
      for (int j = 0; j < 12; ++j) d = fmaf(Jp[n][j], jq[j], d);
      tpq = fmaf(d, d, tpq);
    }
  }

  float Dv[12], Db[12];
  #pragma unroll
  for (int j = 0; j < 12; ++j) Dv[j] = expf(-lvd[j]);

  float mh = 0.f;
  #pragma unroll
  for (int i = 0; i < 12; ++i) mh += Sq[i * (i + 1) / 2 + i] + Dv[i];
  float norm_H = fmaxf(mh * (1.f / 12.f), 1e-6f);
  #pragma unroll
  for (int i = 0; i < 12; ++i) Sq[i * (i + 1) / 2 + i] += Dv[i] + 1e-3f * norm_H;
  float sumDb = 0.f;
  #pragma unroll
  for (int j = 0; j < 12; ++j) { Db[j] = Dv[j] + 1e-3f * norm_H; sumDb += Db[j]; }

  float M[21];
  #pragma unroll
  for (int n = 0; n < 6; ++n)
    #pragma unroll
    for (int mm = 0; mm <= n; ++mm) {
      float acc = 0.f;
      #pragma unroll
      for (int j = 0; j < 12; ++j) acc = fmaf(Jp[n][j], Jp[mm][j], acc);
      M[n * (n + 1) / 2 + mm] = acc;
    }
  float md = 0.f;
  #pragma unroll
  for (int i = 0; i < 6; ++i) md += M[i * (i + 1) / 2 + i];
  float norm_M = fmaxf(md * (1.f / 6.f) + EPSP, 1e-6f);
  #pragma unroll
  for (int i = 0; i < 6; ++i) M[i * (i + 1) / 2 + i] += EPSP + 1e-3f * norm_M;

  float trace_p = 0.f;
  #pragma unroll
  for (int n = 0; n < 6; ++n)
    #pragma unroll
    for (int j = 0; j < 12; ++j)
      trace_p = fmaf(Jp[n][j] * Jp[n][j], Db[j], trace_p);

  float trace = (EPSP + 1e-3f * norm_M) * (sumDb + tq) + trace_p + tpq;

  // Cholesky 6x6 (M), packed lower-tri, fully unrolled
  float ldM = 0.f;
  #pragma unroll
  for (int jc = 0; jc < 6; ++jc) {
    float d = M[jc * (jc + 1) / 2 + jc];
    #pragma unroll
    for (int k = 0; k < jc; ++k) d -= M[jc * (jc + 1) / 2 + k] * M[jc * (jc + 1) / 2 + k];
    d = sqrtf(d);
    ldM += logf(d);
    float di = 1.f / d;
    M[jc * (jc + 1) / 2 + jc] = d;
    #pragma unroll
    for (int i2 = jc + 1; i2 < 6; ++i2) {
      float v = M[i2 * (i2 + 1) / 2 + jc];
      #pragma unroll
      for (int k = 0; k < jc; ++k) v -= M[i2 * (i2 + 1) / 2 + k] * M[jc * (jc + 1) / 2 + k];
      M[i2 * (i2 + 1) / 2 + jc] = v * di;
    }
  }

  // Cholesky 12x12 (H) in place on Sq
  float ldH = 0.f;
  #pragma unroll
  for (int jc = 0; jc < 12; ++jc) {
    float d = Sq[jc * (jc + 1) / 2 + jc];
    #pragma unroll
    for (int k = 0; k < jc; ++k) d -= Sq[jc * (jc + 1) / 2 + k] * Sq[jc * (jc + 1) / 2 + k];
    d = sqrtf(d);
    ldH += logf(d);
    float di = 1.f / d;
    Sq[jc * (jc + 1) / 2 + jc] = d;
    #pragma unroll
    for (int i2 = jc + 1; i2 < 12; ++i2) {
      float v = Sq[i2 * (i2 + 1) / 2 + jc];
      #pragma unroll
      for (int k = 0; k < jc; ++k) v -= Sq[i2 * (i2 + 1) / 2 + k] * Sq[jc * (jc + 1) / 2 + k];
      Sq[i2 * (i2 + 1) / 2 + jc] = v * di;
    }
  }

  float logdet_p = 2.f * ldM + 6.f * logf(EPSP);
  float logdet_q = 2.f * ldH;
  float kl = 0.5f * (trace - (logdet_p + logdet_q) - 12.f);
  out_kl[elem] = kl;                     // fp32 output
}

// ---------------------------------------------------------------------
extern "C" void kernel_launch(void* const* d_in, const int* in_sizes, int n_in,
                              void* d_out, int out_size, void* d_ws, size_t ws_size,
                              hipStream_t stream) {
  (void)in_sizes; (void)n_in; (void)out_size; (void)ws_size;
  float* y    = (float*)d_in[0];   // consumed then overwritten with z
  float* Jp   = (float*)d_in[1];   // consumed then overwritten with pullback Jp
  const float* W1   = (const float*)d_in[2];
  const float* b1   = (const float*)d_in[3];
  const float* W2   = (const float*)d_in[4];
  const float* b2   = (const float*)d_in[5];
  const float* W3   = (const float*)d_in[6];
  const float* b3   = (const float*)d_in[7];
  const float* Wsym = (const float*)d_in[8];
  const float* lvd  = (const float*)d_in[9];
  float* out = (float*)d_out;      // fp32 outputs: [log_prob (B), kl (B)]

  float* ws_sum = (float*)d_ws;    // single float: global sum(Jp^2)
  hipMemsetAsync(d_ws, 0, 4, stream);

  hipFuncSetAttribute((const void*)flow_kernel,
                      hipFuncAttributeMaxDynamicSharedMemorySize, SMEM_BYTES);

  flow_kernel<<<256, 512, SMEM_BYTES, stream>>>(
      y, Jp, W1, b1, W2, b2, W3, b3, ws_sum, out);
  kl_kernel<<<64, 256, 0, stream>>>(y, Jp, Wsym, lvd, ws_sum, out + BTOT);
}

// Round 4
// 4175.627 us; speedup vs baseline: 1.3191x; 1.3191x over previous
//
#include <hip/hip_runtime.h>
#include <hip/hip_bf16.h>
#include <math.h>

#define BTOT   16384
#define NLAYER 24
#define HID    192
#define NDIN   12
#define NBASE  66
#define EPSP   1e-3f

// ---------------- LDS layout (bytes) ----------------
// JST=200: j-stride (bf16) for W2t/G rows -> 400B row stride, 16B aligned,
// bank phase 100 dw == 4 mod 32 -> worst 2-way (free). H1ST=66 for h1/mask.
#define JST 200
#define H1ST 66
#define OB_W2T 0        // ushort[192*200] 76800   W2^T bf16 [k][j]
#define OB_G   76800    // ushort[64*200]  25600   G [e][j] then Gh1 [e][k]
#define OB_H1  102400   // ushort[192*66]  25344   h1 bf16 [row][e] (also mask)
#define OB_R   127744   // float[72*64]    18432   cotangent rows
#define OB_PRM 146176   // float[12*64]    3072    prm sums (LDS atomics)
#define OB_GP  149248   // float[12*64]    3072    g_prm
#define OB_GZ  152320   // float[6*64]     1536    g_z1 sums (LDS atomics)
#define OB_Z   153856   // float[12*64]    3072    z state
#define OB_LD  156928   // float[64]       256     logdet acc
#define OB_RED 157184   // float[8]        32
#define SMEM_BYTES 157216

typedef __attribute__((ext_vector_type(8))) short s8v;
typedef __attribute__((ext_vector_type(4))) float f4v;
#define MFMA16(a,b,c) __builtin_amdgcn_mfma_f32_16x16x32_bf16(a,b,c,0,0,0)

__device__ __forceinline__ unsigned short f2bf(float f) {
  unsigned u = __builtin_bit_cast(unsigned, f);
  u += 0x7fffu + ((u >> 16) & 1u);          // RNE
  return (unsigned short)(u >> 16);
}
__device__ __forceinline__ float bf2f(unsigned short h) {
  unsigned u = ((unsigned)h) << 16;
  return __builtin_bit_cast(float, u);
}

// ---------------------------------------------------------------------
// flow_kernel: block = 64 elements (lane = element), 8 waves.
// Inverse coupling fused with forward-VJP; the 6 W2^T GEMMs per layer run
// on bf16 MFMA (A = W2^T bf16 LDS, B = G bf16 [e][j]); rest fp32 VALU.
__global__ __launch_bounds__(512) void flow_kernel(
    float* __restrict__ yz, float* __restrict__ jp,
    const float* __restrict__ W1, const float* __restrict__ b1,
    const float* __restrict__ W2, const float* __restrict__ b2,
    const float* __restrict__ W3, const float* __restrict__ b3,
    float* __restrict__ ws_sum, float* __restrict__ out_lp) {
  extern __shared__ char smraw[];
  unsigned short* sW2t = (unsigned short*)(smraw + OB_W2T);
  unsigned short* sGb  = (unsigned short*)(smraw + OB_G);
  unsigned short* sH1b = (unsigned short*)(smraw + OB_H1);
  float* sR   = (float*)(smraw + OB_R);
  float* sPRM = (float*)(smraw + OB_PRM);
  float* sGP  = (float*)(smraw + OB_GP);
  float* sGZ  = (float*)(smraw + OB_GZ);
  float* sZ   = (float*)(smraw + OB_Z);
  float* sLD  = (float*)(smraw + OB_LD);
  float* sRed = (float*)(smraw + OB_RED);

  const int tid  = threadIdx.x;
  const int e    = tid & 63;                                 // lane = element
  const int w    = __builtin_amdgcn_readfirstlane(tid >> 6); // wave 0..7
  const int jb   = 24 * w;                                   // row slab
  const int blk  = blockIdx.x;
  const int elem = blk * 64 + e;
  const int lm   = e & 15, lq = e >> 4;                      // MFMA lane coords

  // ---- init ----
  if (w == 0) {
    #pragma unroll
    for (int i = 0; i < 12; ++i) sZ[i * 64 + e] = yz[elem * 12 + i];
    sLD[e] = 0.f;
  }
  for (int idx = tid; idx < 72 * 64; idx += 512) {
    int rt = idx >> 6, ee = idx & 63;
    sR[idx] = jp[(blk * 64 + ee) * 72 + rt];
  }
  __syncthreads();

  unsigned m2 = 0;
  float es_r = 0.f, tf_r = 0.f, r2_r = 0.f;  // live in tid<384 threads

  for (int l = NLAYER - 1; l >= 0; --l) {
    const float* W1l = W1 + l * HID * 6;
    const float* b1l = b1 + l * HID;
    const float* W2l = W2 + l * HID * HID;
    const float* b2l = b2 + l * HID;
    const float* W3l = W3 + l * NDIN * HID;
    const float* b3l = b3 + l * NDIN;

    // ---- stage W2^T bf16 into LDS + zero sPRM + F1 ----
    for (int t = tid; t < 192 * 48; t += 512) {
      int j = t / 48, k4 = (t - (t / 48) * 48) * 4;
      float4 v = *(const float4*)(W2l + j * HID + k4);
      int base = k4 * JST + j;
      sW2t[base]           = f2bf(v.x);
      sW2t[base + JST]     = f2bf(v.y);
      sW2t[base + 2 * JST] = f2bf(v.z);
      sW2t[base + 3 * JST] = f2bf(v.w);
    }
    sPRM[tid] = 0.f;
    if (tid < 256) sPRM[512 + tid] = 0.f;
    {
      float z1v[6];
      #pragma unroll
      for (int i = 0; i < 6; ++i) z1v[i] = sZ[(6 + i) * 64 + e];
      #pragma unroll
      for (int jj = 0; jj < 24; ++jj) {
        int j = jb + jj;
        float acc = b1l[j];
        #pragma unroll
        for (int i = 0; i < 6; ++i) acc = fmaf(W1l[j * 6 + i], z1v[i], acc);
        sH1b[j * H1ST + e] = f2bf(fmaxf(acc, 0.f));
      }
    }
    __syncthreads();

    // ---- F2: h2 = relu(W2 h1 + b2) fp32; W3 partials via LDS atomics ----
    {
      float acc[24];
      #pragma unroll
      for (int jj = 0; jj < 24; ++jj) acc[jj] = b2l[jb + jj];
      for (int k = 0; k < HID; ++k) {
        float h1k = bf2f(sH1b[k * H1ST + e]);
        #pragma unroll
        for (int jj = 0; jj < 24; ++jj)
          acc[jj] = fmaf(W2l[(jb + jj) * HID + k], h1k, acc[jj]);
      }
      float h2v[24];
      m2 = 0;
      #pragma unroll
      for (int jj = 0; jj < 24; ++jj) {
        m2 |= (acc[jj] > 0.f ? 1u : 0u) << jj;
        h2v[jj] = fmaxf(acc[jj], 0.f);
      }
      #pragma unroll
      for (int t = 0; t < 12; ++t) {
        const float* w3r = W3l + t * HID + jb;
        float pp = 0.f;
        #pragma unroll
        for (int jj = 0; jj < 24; ++jj) pp = fmaf(w3r[jj], h2v[jj], pp);
        atomicAdd(&sPRM[t * 64 + e], pp);
      }
    }
    __syncthreads();

    // ---- U: coupling update + V1(r=0); es/tf/r2 stay in registers ----
    if (tid < 384) {
      int i = w;
      float shift = b3l[2 * i] + sPRM[(2 * i) * 64 + e];
      float sraw  = b3l[2 * i + 1] + sPRM[(2 * i + 1) * 64 + e];
      float s   = 2.f * tanhf(0.5f * sraw);
      es_r      = expf(s);
      float en  = expf(-s);
      float fac = 1.f - 0.25f * s * s;
      float z2o = sZ[i * 64 + e];
      float z1o = sZ[(6 + i) * 64 + e];
      float tv  = z2o - shift;
      sZ[i * 64 + e]       = z1o;
      sZ[(6 + i) * 64 + e] = tv * en;
      tf_r = tv * fac;
      atomicAdd(&sLD[e], -s);
      // V1 for r=0
      float r1 = sR[i * 64 + e];
      r2_r = sR[(6 + i) * 64 + e];
      sGP[(2 * i) * 64 + e]     = r1;
      sGP[(2 * i + 1) * 64 + e] = r1 * tf_r;
      sR[(6 + i) * 64 + e]      = r1 * es_r;
      sGZ[i * 64 + e] = 0.f;
    }
    __syncthreads();

    // ---- VJP rows ----
    for (int r = 0; r < 6; ++r) {
      // V2: G = mask2 .* (W3^T g_prm) -> bf16 [e][j]
      {
        float gp[12];
        #pragma unroll
        for (int t = 0; t < 12; ++t) gp[t] = sGP[t * 64 + e];
        float g[24];
        #pragma unroll
        for (int jj = 0; jj < 24; ++jj) g[jj] = 0.f;
        #pragma unroll
        for (int t = 0; t < 12; ++t) {
          const float* w3r = W3l + t * HID + jb;
          #pragma unroll
          for (int jj = 0; jj < 24; ++jj) g[jj] = fmaf(w3r[jj], gp[t], g[jj]);
        }
        unsigned* dstw = (unsigned*)sGb;
        int base = (e * JST + jb) >> 1;
        #pragma unroll
        for (int p = 0; p < 12; ++p) {
          int jj = 2 * p;
          float v0 = ((m2 >> jj) & 1) ? g[jj] : 0.f;
          float v1 = ((m2 >> (jj + 1)) & 1) ? g[jj + 1] : 0.f;
          dstw[base + p] = (unsigned)f2bf(v0) | ((unsigned)f2bf(v1) << 16);
        }
      }
      __syncthreads();

      // V3 MFMA: D[k,e] = sum_j W2t[k][j] * G[j][e]
      const int wr = w >> 1, wc = w & 1;
      f4v acc00{0,0,0,0}, acc01{0,0,0,0}, acc10{0,0,0,0},
          acc11{0,0,0,0}, acc20{0,0,0,0}, acc21{0,0,0,0};
      #pragma unroll
      for (int kk = 0; kk < 6; ++kk) {
        int jo = kk * 32 + lq * 8;
        s8v a0 = *(const s8v*)&sW2t[(wr * 16 + lm) * JST + jo];
        s8v a1 = *(const s8v*)&sW2t[((wr + 4) * 16 + lm) * JST + jo];
        s8v a2 = *(const s8v*)&sW2t[((wr + 8) * 16 + lm) * JST + jo];
        s8v b0 = *(const s8v*)&sGb[((2 * wc) * 16 + lm) * JST + jo];
        s8v b1v = *(const s8v*)&sGb[((2 * wc + 1) * 16 + lm) * JST + jo];
        acc00 = MFMA16(a0, b0, acc00);  acc01 = MFMA16(a0, b1v, acc01);
        acc10 = MFMA16(a1, b0, acc10);  acc11 = MFMA16(a1, b1v, acc11);
        acc20 = MFMA16(a2, b0, acc20);  acc21 = MFMA16(a2, b1v, acc21);
      }
      __syncthreads();   // all waves done reading sGb (G)

      // epilogue: mask1 (h1 bits) and write Gh1 bf16 as [e][k]
      {
        f4v* accs[6] = {&acc00, &acc01, &acc10, &acc11, &acc20, &acc21};
        #pragma unroll
        for (int p = 0; p < 3; ++p) {
          int mtb = (wr + 4 * p) * 16;
          #pragma unroll
          for (int q = 0; q < 2; ++q) {
            int eo = (2 * wc + q) * 16 + lm;
            f4v a = *accs[p * 2 + q];
            #pragma unroll
            for (int i = 0; i < 4; ++i) {
              int ko = mtb + lq * 4 + i;
              float v = (sH1b[ko * H1ST + eo] != 0) ? a[i] : 0.f;
              sGb[eo * JST + ko] = f2bf(v);
            }
          }
        }
      }
      __syncthreads();

      // V4: g_z1 partials = W1^T Gh1 (VALU, LDS atomics)
      {
        const s8v* gh = (const s8v*)&sGb[e * JST + jb];
        s8v g0 = gh[0], g1 = gh[1], g2 = gh[2];
        float pz[6] = {0.f, 0.f, 0.f, 0.f, 0.f, 0.f};
        #pragma unroll
        for (int kk = 0; kk < 24; ++kk) {
          unsigned short bits = (unsigned short)(kk < 8 ? g0[kk]
                                : kk < 16 ? g1[kk - 8] : g2[kk - 16]);
          float gv = bf2f(bits);
          const float* w1r = W1l + (jb + kk) * 6;
          #pragma unroll
          for (int i = 0; i < 6; ++i) pz[i] = fmaf(w1r[i], gv, pz[i]);
        }
        #pragma unroll
        for (int i = 0; i < 6; ++i) atomicAdd(&sGZ[i * 64 + e], pz[i]);
      }
      __syncthreads();

      // V5 (+ V1 of next r)
      if (tid < 384) {
        int i = w;
        sR[(r * 12 + i) * 64 + e] = r2_r + sGZ[i * 64 + e];
        sGZ[i * 64 + e] = 0.f;
        if (r < 5) {
          float r1 = sR[((r + 1) * 12 + i) * 64 + e];
          r2_r = sR[((r + 1) * 12 + 6 + i) * 64 + e];
          sGP[(2 * i) * 64 + e]     = r1;
          sGP[(2 * i + 1) * 64 + e] = r1 * tf_r;
          sR[((r + 1) * 12 + 6 + i) * 64 + e] = r1 * es_r;
        }
      }
      __syncthreads();
    }
  }

  // ---- epilogue ----
  if (tid == 0) sRed[0] = 0.f;
  if (w == 0) {
    float zsq = 0.f;
    #pragma unroll
    for (int i = 0; i < 12; ++i) {
      float zi = sZ[i * 64 + e];
      zsq = fmaf(zi, zi, zsq);
      yz[elem * 12 + i] = zi;
    }
    out_lp[elem] = sLD[e] - 11.027262398456072f - 0.5f * zsq;
  }
  __syncthreads();
  float part = 0.f;
  for (int idx = tid; idx < 72 * 64; idx += 512) {
    int rt = idx >> 6, ee = idx & 63;
    float v = sR[idx];
    jp[(blk * 64 + ee) * 72 + rt] = v;
    part = fmaf(v, v, part);
  }
  #pragma unroll
  for (int off = 32; off > 0; off >>= 1) part += __shfl_down(part, off, 64);
  if ((tid & 63) == 0) atomicAdd(&sRed[0], part);
  __syncthreads();
  if (tid == 0) atomicAdd(ws_sum, sRed[0]);
}

// ---------------------------------------------------------------------
// kl_kernel: one thread per element (unchanged from R3 PASS).
__global__ __launch_bounds__(256) void kl_kernel(
    const float* __restrict__ zin, const float* __restrict__ jpin,
    const float* __restrict__ Wsym, const float* __restrict__ lvd,
    const float* __restrict__ ws_sum, float* __restrict__ out_kl) {
  int elem = blockIdx.x * 256 + threadIdx.x;
  float z[12];
  #pragma unroll
  for (int i = 0; i < 12; ++i) z[i] = zin[elem * 12 + i];
  float scale = 1.0f / sqrtf(ws_sum[0]);
  float Jp[6][12];
  #pragma unroll
  for (int n = 0; n < 6; ++n)
    #pragma unroll
    for (int j = 0; j < 12; ++j)
      Jp[n][j] = jpin[elem * 72 + n * 12 + j] * scale;

  float Sq[78];
  #pragma unroll
  for (int i = 0; i < 78; ++i) Sq[i] = 0.f;
  float tq = 0.f, tpq = 0.f;

  for (int m = 0; m < NBASE; ++m) {
    const float* Wm = Wsym + m * 144;
    float jq[12];
    #pragma unroll
    for (int j = 0; j < 12; ++j) {
      float acc = 0.f;
      #pragma unroll
      for (int i = 0; i < 12; ++i)
        acc = fmaf(Wm[j * 12 + i] - Wm[i * 12 + j], z[i], acc);
      jq[j] = acc;
    }
    #pragma unroll
    for (int i = 0; i < 12; ++i) {
      tq = fmaf(jq[i], jq[i], tq);
      #pragma unroll
      for (int j = 0; j <= i; ++j)
        Sq[i * (i + 1) / 2 + j] = fmaf(jq[i], jq[j], Sq[i * (i + 1) / 2 + j]);
    }
    #pragma unroll
    for (int n = 0; n < 6; ++n) {
      float d = 0.f;
      #pragma unroll
      for (int j = 0; j < 12; ++j) d = fmaf(Jp[n][j], jq[j], d);
      tpq = fmaf(d, d, tpq);
    }
  }

  float Dv[12], Db[12];
  #pragma unroll
  for (int j = 0; j < 12; ++j) Dv[j] = expf(-lvd[j]);

  float mh = 0.f;
  #pragma unroll
  for (int i = 0; i < 12; ++i) mh += Sq[i * (i + 1) / 2 + i] + Dv[i];
  float norm_H = fmaxf(mh * (1.f / 12.f), 1e-6f);
  #pragma unroll
  for (int i = 0; i < 12; ++i) Sq[i * (i + 1) / 2 + i] += Dv[i] + 1e-3f * norm_H;
  float sumDb = 0.f;
  #pragma unroll
  for (int j = 0; j < 12; ++j) { Db[j] = Dv[j] + 1e-3f * norm_H; sumDb += Db[j]; }

  float M[21];
  #pragma unroll
  for (int n = 0; n < 6; ++n)
    #pragma unroll
    for (int mm = 0; mm <= n; ++mm) {
      float acc = 0.f;
      #pragma unroll
      for (int j = 0; j < 12; ++j) acc = fmaf(Jp[n][j], Jp[mm][j], acc);
      M[n * (n + 1) / 2 + mm] = acc;
    }
  float md = 0.f;
  #pragma unroll
  for (int i = 0; i < 6; ++i) md += M[i * (i + 1) / 2 + i];
  float norm_M = fmaxf(md * (1.f / 6.f) + EPSP, 1e-6f);
  #pragma unroll
  for (int i = 0; i < 6; ++i) M[i * (i + 1) / 2 + i] += EPSP + 1e-3f * norm_M;

  float trace_p = 0.f;
  #pragma unroll
  for (int n = 0; n < 6; ++n)
    #pragma unroll
    for (int j = 0; j < 12; ++j)
      trace_p = fmaf(Jp[n][j] * Jp[n][j], Db[j], trace_p);

  float trace = (EPSP + 1e-3f * norm_M) * (sumDb + tq) + trace_p + tpq;

  float ldM = 0.f;
  #pragma unroll
  for (int jc = 0; jc < 6; ++jc) {
    float d = M[jc * (jc + 1) / 2 + jc];
    #pragma unroll
    for (int k = 0; k < jc; ++k) d -= M[jc * (jc + 1) / 2 + k] * M[jc * (jc + 1) / 2 + k];
    d = sqrtf(d);
    ldM += logf(d);
    float di = 1.f / d;
    M[jc * (jc + 1) / 2 + jc] = d;
    #pragma unroll
    for (int i2 = jc + 1; i2 < 6; ++i2) {
      float v = M[i2 * (i2 + 1) / 2 + jc];
      #pragma unroll
      for (int k = 0; k < jc; ++k) v -= M[i2 * (i2 + 1) / 2 + k] * M[jc * (jc + 1) / 2 + k];
      M[i2 * (i2 + 1) / 2 + jc] = v * di;
    }
  }

  float ldH = 0.f;
  #pragma unroll
  for (int jc = 0; jc < 12; ++jc) {
    float d = Sq[jc * (jc + 1) / 2 + jc];
    #pragma unroll
    for (int k = 0; k < jc; ++k) d -= Sq[jc * (jc + 1) / 2 + k] * Sq[jc * (jc + 1) / 2 + k];
    d = sqrtf(d);
    ldH += logf(d);
    float di = 1.f / d;
    Sq[jc * (jc + 1) / 2 + jc] = d;
    #pragma unroll
    for (int i2 = jc + 1; i2 < 12; ++i2) {
      float v = Sq[i2 * (i2 + 1) / 2 + jc];
      #pragma unroll
      for (int k = 0; k < jc; ++k) v -= Sq[i2 * (i2 + 1) / 2 + k] * Sq[jc * (jc + 1) / 2 + k];
      Sq[i2 * (i2 + 1) / 2 + jc] = v * di;
    }
  }

  float logdet_p = 2.f * ldM + 6.f * logf(EPSP);
  float logdet_q = 2.f * ldH;
  out_kl[elem] = 0.5f * (trace - (logdet_p + logdet_q) - 12.f);
}

// ---------------------------------------------------------------------
extern "C" void kernel_launch(void* const* d_in, const int* in_sizes, int n_in,
                              void* d_out, int out_size, void* d_ws, size_t ws_size,
                              hipStream_t stream) {
  (void)in_sizes; (void)n_in; (void)out_size; (void)ws_size;
  float* y    = (float*)d_in[0];   // consumed, then overwritten with z
  float* Jp   = (float*)d_in[1];   // consumed, then overwritten with pullback Jp
  const float* W1   = (const float*)d_in[2];
  const float* b1   = (const float*)d_in[3];
  const float* W2   = (const float*)d_in[4];
  const float* b2   = (const float*)d_in[5];
  const float* W3   = (const float*)d_in[6];
  const float* b3   = (const float*)d_in[7];
  const float* Wsym = (const float*)d_in[8];
  const float* lvd  = (const float*)d_in[9];
  float* out = (float*)d_out;      // fp32: [log_prob (B), kl (B)]

  float* ws_sum = (float*)d_ws;
  hipMemsetAsync(d_ws, 0, 4, stream);

  hipFuncSetAttribute((const void*)flow_kernel,
                      hipFuncAttributeMaxDynamicSharedMemorySize, SMEM_BYTES);

  flow_kernel<<<256, 512, SMEM_BYTES, stream>>>(
      y, Jp, W1, b1, W2, b2, W3, b3, ws_sum, out);
  kl_kernel<<<64, 256, 0, stream>>>(y, Jp, Wsym, lvd, ws_sum, out + BTOT);
}

// Round 5
// 2936.099 us; speedup vs baseline: 1.8759x; 1.4222x over previous
//
#include <hip/hip_runtime.h>
#include <hip/hip_bf16.h>
#include <math.h>

#define BTOT   16384
#define NLAYER 24
#define HID    192
#define NDIN   12
#define NBASE  66
#define EPSP   1e-3f

// ---------------- LDS layout (bytes), 79,392 total -> 2 blocks/CU ----------
#define EST 200          // e-row stride (shorts) for sH1b/sGb: 192+8 pad
#define OB_H1  0         // ushort[64*200] 25600 : h1 bf16 [e][k]
#define OB_G   25600     // ushort[64*200] 25600 : h2 then G bf16 [e][j]
#define OB_R   51200     // float[72*64]  18432  : cotangent rows [rt][e]
#define OB_W1  69632     // ushort[192*8]  3072  : W1 bf16, rows padded to 8
#define OB_PRM 72704     // float[12*64]   3072  : prm sums; then tf@(2i), es@(2i+1)
#define OB_GZ  75776     // float[6*64]    1536  : g_z1 partial sums (atomics)
#define OB_Z1  77312     // float[6*64]    1536  : z[6..12) for next F1
#define OB_LD  78848     // float[64]       256  : logdet acc
#define OB_ZQ  79104     // float[64]       256  : sum z^2
#define OB_RED 79360     // float[8]         32
#define SMEM_BYTES 79392

typedef __attribute__((ext_vector_type(8))) short s8v;
typedef __attribute__((ext_vector_type(4))) float f4v;
#define MFMA16(a,b,c) __builtin_amdgcn_mfma_f32_16x16x32_bf16(a,b,c,0,0,0)

__device__ __forceinline__ unsigned short f2bf(float f) {
  unsigned u = __builtin_bit_cast(unsigned, f);
  u += 0x7fffu + ((u >> 16) & 1u);          // RNE
  return (unsigned short)(u >> 16);
}
__device__ __forceinline__ float bf2f(unsigned short h) {
  unsigned u = ((unsigned)h) << 16;
  return __builtin_bit_cast(float, u);
}
__device__ __forceinline__ unsigned pk2(float a, float b) {
  return (unsigned)f2bf(a) | ((unsigned)f2bf(b) << 16);
}

// ---------------------------------------------------------------------
// prep: W2 -> bf16 (orig layout) and bf16 transpose, into workspace.
__global__ void prep_kernel(const float* __restrict__ W2,
                            unsigned short* __restrict__ w2b,
                            unsigned short* __restrict__ w2t) {
  int idx = blockIdx.x * 256 + threadIdx.x;   // 884736 exact
  int l   = idx / (HID * HID);
  int rem = idx - l * HID * HID;
  int k   = rem / HID;
  int j   = rem - k * HID;
  w2b[idx] = f2bf(W2[idx]);                         // [l][j][k]
  w2t[idx] = f2bf(W2[l * HID * HID + j * HID + k]); // [l][k][j]
}

// ---------------------------------------------------------------------
__global__ __launch_bounds__(512, 4) void flow_kernel(
    float* __restrict__ yz, float* __restrict__ jp,
    const float* __restrict__ W1, const float* __restrict__ b1,
    const float* __restrict__ b2,
    const float* __restrict__ W3, const float* __restrict__ b3,
    const unsigned short* __restrict__ w2b,
    const unsigned short* __restrict__ w2t,
    float* __restrict__ ws_sum, float* __restrict__ out_lp) {
  extern __shared__ char smraw[];
  unsigned short* sH1b = (unsigned short*)(smraw + OB_H1);
  unsigned short* sGb  = (unsigned short*)(smraw + OB_G);
  float* sR   = (float*)(smraw + OB_R);
  float* sPRM = (float*)(smraw + OB_PRM);
  float* sGZ  = (float*)(smraw + OB_GZ);
  float* sZ1  = (float*)(smraw + OB_Z1);
  float* sLD  = (float*)(smraw + OB_LD);
  float* sZQ  = (float*)(smraw + OB_ZQ);
  float* sRed = (float*)(smraw + OB_RED);

  const int tid  = threadIdx.x;
  const int e    = tid & 63;
  const int w    = __builtin_amdgcn_readfirstlane(tid >> 6);
  const int jb   = 24 * w;                       // per-thread j-slab (S2/V2)
  const int lm   = e & 15, lq = e >> 4;          // MFMA lane coords
  const int mtg  = (w & 3) * 3;                  // 3 m-tiles of 12
  const int ntg  = (w >> 2) * 2;                 // 2 n-tiles of 4
  const int blk  = blockIdx.x;
  const int elem = blk * 64 + e;

  // ---- init ----
  float z_a = 0.f, z_b = 0.f;                    // z[i], z[6+i] for thread (i=w<6)
  if (w < 6) {
    z_a = yz[elem * 12 + w];
    z_b = yz[elem * 12 + 6 + w];
    sZ1[w * 64 + e] = z_b;
    sGZ[w * 64 + e] = 0.f;
  }
  if (w == 0) { sLD[e] = 0.f; sZQ[e] = 0.f; }
  if (tid == 0) sRed[0] = 0.f;
  sPRM[tid] = 0.f;
  if (tid < 256) sPRM[512 + tid] = 0.f;
  for (int idx = tid; idx < 72 * 64; idx += 512) {
    int rt = idx >> 6, ee = idx & 63;
    sR[idx] = jp[(blk * 64 + ee) * 72 + rt];
  }
  __syncthreads();

  unsigned m2 = 0;

  for (int l = NLAYER - 1; l >= 0; --l) {
    const float* W1l = W1 + l * HID * 6;
    const float* b1l = b1 + l * HID;
    const float* b2l = b2 + l * HID;
    const float* W3l = W3 + l * NDIN * HID;
    const float* b3l = b3 + l * NDIN;
    const unsigned short* w2bl = w2b + l * HID * HID;
    const unsigned short* w2tl = w2t + l * HID * HID;

    // ======== F1 phase: stage W1 bf16, zero sPRM, h1 = relu(W1 z1+b1) ====
    if (tid < 192) {
      const float* wr = W1l + tid * 6;
      uint4 pk;
      pk.x = pk2(wr[0], wr[1]); pk.y = pk2(wr[2], wr[3]);
      pk.z = pk2(wr[4], wr[5]); pk.w = 0;
      *(uint4*)(smraw + OB_W1 + tid * 16) = pk;
    }
    sPRM[tid] = 0.f;
    if (tid < 256) sPRM[512 + tid] = 0.f;
    {
      float z1v[6];
      #pragma unroll
      for (int i = 0; i < 6; ++i) z1v[i] = sZ1[i * 64 + e];
      #pragma unroll
      for (int jj = 0; jj < 24; ++jj) {
        int j = jb + jj;                          // wave-uniform -> s_load W1
        float acc = b1l[j];
        #pragma unroll
        for (int i = 0; i < 6; ++i) acc = fmaf(W1l[j * 6 + i], z1v[i], acc);
        sH1b[e * EST + j] = f2bf(fmaxf(acc, 0.f));
      }
    }
    __syncthreads();

    // ======== S1: F2 via MFMA: h2[j][e] = relu(W2 h1 + b2) -> sGb[e][j] ==
    {
      f4v acc[3][2] = {{{0,0,0,0},{0,0,0,0}},{{0,0,0,0},{0,0,0,0}},
                       {{0,0,0,0},{0,0,0,0}}};
      #pragma unroll
      for (int kk = 0; kk < 6; ++kk) {
        int jo = kk * 32 + lq * 8;
        s8v A[3], B[2];
        #pragma unroll
        for (int p = 0; p < 3; ++p)
          A[p] = *(const s8v*)(w2bl + ((mtg + p) * 16 + lm) * HID + jo);
        #pragma unroll
        for (int q = 0; q < 2; ++q)
          B[q] = *(const s8v*)&sH1b[((ntg + q) * 16 + lm) * EST + jo];
        #pragma unroll
        for (int p = 0; p < 3; ++p)
          #pragma unroll
          for (int q = 0; q < 2; ++q)
            acc[p][q] = MFMA16(A[p], B[q], acc[p][q]);
      }
      #pragma unroll
      for (int p = 0; p < 3; ++p) {
        int jb2 = (mtg + p) * 16 + lq * 4;
        float bb[4];
        #pragma unroll
        for (int rg = 0; rg < 4; ++rg) bb[rg] = b2l[jb2 + rg];
        #pragma unroll
        for (int q = 0; q < 2; ++q) {
          int e2 = (ntg + q) * 16 + lm;
          float h0 = fmaxf(acc[p][q][0] + bb[0], 0.f);
          float h1 = fmaxf(acc[p][q][1] + bb[1], 0.f);
          float h2 = fmaxf(acc[p][q][2] + bb[2], 0.f);
          float h3 = fmaxf(acc[p][q][3] + bb[3], 0.f);
          unsigned* dst = (unsigned*)sGb + ((e2 * EST + jb2) >> 1);
          dst[0] = pk2(h0, h1);
          dst[1] = pk2(h2, h3);
        }
      }
    }
    __syncthreads();

    // ======== S2: prm partials from h2 (bf16) + capture mask2 ============
    {
      s8v hh[3];
      #pragma unroll
      for (int c = 0; c < 3; ++c)
        hh[c] = *(const s8v*)&sGb[e * EST + jb + c * 8];
      float h2v[24];
      m2 = 0;
      #pragma unroll
      for (int jj = 0; jj < 24; ++jj) {
        unsigned short bits = (unsigned short)hh[jj / 8][jj % 8];
        h2v[jj] = bf2f(bits);
        m2 |= (bits != 0 ? 1u : 0u) << jj;
      }
      #pragma unroll
      for (int t = 0; t < 12; ++t) {
        const float* w3r = W3l + t * HID + jb;
        float pp = 0.f;
        #pragma unroll
        for (int jj = 0; jj < 24; ++jj) pp = fmaf(w3r[jj], h2v[jj], pp);
        atomicAdd(&sPRM[t * 64 + e], pp);
      }
    }
    __syncthreads();

    // ======== U: coupling update; sPRM slots become tf@(2i), es@(2i+1) ===
    if (w < 6) {
      int i = w;
      float sh = b3l[2 * i]     + sPRM[(2 * i) * 64 + e];
      float sr = b3l[2 * i + 1] + sPRM[(2 * i + 1) * 64 + e];
      float s  = 2.f * tanhf(0.5f * sr);
      float es = expf(s), en = expf(-s);
      float tv = z_a - sh;
      z_a = z_b;
      z_b = tv * en;
      sZ1[i * 64 + e] = z_b;
      sPRM[(2 * i) * 64 + e]     = tv * (1.f - 0.25f * s * s);  // tf
      sPRM[(2 * i + 1) * 64 + e] = es;                          // es
      atomicAdd(&sLD[e], -s);
    }
    __syncthreads();

    // ======== VJP rows: {V2} b {V3+epi} b {V5 + V2(next)} b ... ==========
    // V2 lambda-style block for row r:
    #define DO_V2(rr)                                                        \
    {                                                                        \
      float gp[12];                                                          \
      _Pragma("unroll")                                                      \
      for (int i = 0; i < 6; ++i) {                                          \
        float r1 = sR[((rr) * 12 + i) * 64 + e];                             \
        gp[2 * i]     = r1;                                                  \
        gp[2 * i + 1] = r1 * sPRM[(2 * i) * 64 + e];                         \
      }                                                                      \
      float g[24];                                                           \
      _Pragma("unroll")                                                      \
      for (int jj = 0; jj < 24; ++jj) g[jj] = 0.f;                           \
      _Pragma("unroll")                                                      \
      for (int t = 0; t < 12; ++t) {                                         \
        const float* w3r = W3l + t * HID + jb;                               \
        _Pragma("unroll")                                                    \
        for (int jj = 0; jj < 24; ++jj) g[jj] = fmaf(w3r[jj], gp[t], g[jj]); \
      }                                                                      \
      unsigned* dst = (unsigned*)sGb + ((e * EST + jb) >> 1);                \
      _Pragma("unroll")                                                      \
      for (int pr = 0; pr < 12; ++pr) {                                      \
        int jj = 2 * pr;                                                     \
        float v0 = ((m2 >> jj) & 1) ? g[jj] : 0.f;                           \
        float v1 = ((m2 >> (jj + 1)) & 1) ? g[jj + 1] : 0.f;                 \
        dst[pr] = pk2(v0, v1);                                               \
      }                                                                      \
    }

    DO_V2(0);
    __syncthreads();

    for (int r = 0; r < 6; ++r) {
      // ---- V3 MFMA: D[k][e] = sum_j W2T[k][j] G[e][j]; epi: mask1 + W1^T
      {
        f4v acc[3][2] = {{{0,0,0,0},{0,0,0,0}},{{0,0,0,0},{0,0,0,0}},
                         {{0,0,0,0},{0,0,0,0}}};
        #pragma unroll
        for (int kk = 0; kk < 6; ++kk) {
          int jo = kk * 32 + lq * 8;
          s8v A[3], B[2];
          #pragma unroll
          for (int p = 0; p < 3; ++p)
            A[p] = *(const s8v*)(w2tl + ((mtg + p) * 16 + lm) * HID + jo);
          #pragma unroll
          for (int q = 0; q < 2; ++q)
            B[q] = *(const s8v*)&sGb[((ntg + q) * 16 + lm) * EST + jo];
          #pragma unroll
          for (int p = 0; p < 3; ++p)
            #pragma unroll
            for (int q = 0; q < 2; ++q)
              acc[p][q] = MFMA16(A[p], B[q], acc[p][q]);
        }
        float pz[2][6];
        #pragma unroll
        for (int q = 0; q < 2; ++q)
          #pragma unroll
          for (int i = 0; i < 6; ++i) pz[q][i] = 0.f;

        #pragma unroll
        for (int p = 0; p < 3; ++p) {
          int kb = (mtg + p) * 16 + lq * 4;
          float w1v[4][6];
          #pragma unroll
          for (int rg = 0; rg < 4; ++rg) {     // quad-broadcast LDS reads
            uint4 wr = *(const uint4*)(smraw + OB_W1 + (kb + rg) * 16);
            w1v[rg][0] = bf2f((unsigned short)(wr.x & 0xffff));
            w1v[rg][1] = bf2f((unsigned short)(wr.x >> 16));
            w1v[rg][2] = bf2f((unsigned short)(wr.y & 0xffff));
            w1v[rg][3] = bf2f((unsigned short)(wr.y >> 16));
            w1v[rg][4] = bf2f((unsigned short)(wr.z & 0xffff));
            w1v[rg][5] = bf2f((unsigned short)(wr.z >> 16));
          }
          #pragma unroll
          for (int q = 0; q < 2; ++q) {
            int e2 = (ntg + q) * 16 + lm;
            const unsigned* mp = (const unsigned*)&sH1b[e2 * EST + kb];
            unsigned mm0 = mp[0], mm1 = mp[1];
            unsigned short hb[4] = {
              (unsigned short)(mm0 & 0xffff), (unsigned short)(mm0 >> 16),
              (unsigned short)(mm1 & 0xffff), (unsigned short)(mm1 >> 16)};
            #pragma unroll
            for (int rg = 0; rg < 4; ++rg) {
              float val = hb[rg] ? acc[p][q][rg] : 0.f;
              #pragma unroll
              for (int i = 0; i < 6; ++i)
                pz[q][i] = fmaf(w1v[rg][i], val, pz[q][i]);
            }
          }
        }
        #pragma unroll
        for (int q = 0; q < 2; ++q) {
          int e2 = (ntg + q) * 16 + lm;
          #pragma unroll
          for (int i = 0; i < 6; ++i)
            atomicAdd(&sGZ[i * 64 + e2], pz[q][i]);
        }
      }
      __syncthreads();

      // ---- V5 (update cotangent row r) + V2 of next row ----
      if (w < 6) {
        int i = w;
        float r1  = sR[(r * 12 + i) * 64 + e];
        float r2o = sR[(r * 12 + 6 + i) * 64 + e];
        float es  = sPRM[(2 * i + 1) * 64 + e];
        sR[(r * 12 + i) * 64 + e]     = r2o + sGZ[i * 64 + e];
        sR[(r * 12 + 6 + i) * 64 + e] = r1 * es;
        sGZ[i * 64 + e] = 0.f;
      }
      if (r < 5) { DO_V2(r + 1); }
      __syncthreads();
    }
    #undef DO_V2
  }

  // ---- epilogue ----
  if (w < 6) {
    yz[elem * 12 + w]     = z_a;
    yz[elem * 12 + 6 + w] = z_b;
    atomicAdd(&sZQ[e], fmaf(z_a, z_a, z_b * z_b));
  }
  __syncthreads();
  if (w == 0)
    out_lp[elem] = sLD[e] - 11.027262398456072f - 0.5f * sZQ[e];

  float part = 0.f;
  for (int idx = tid; idx < 72 * 64; idx += 512) {
    int rt = idx >> 6, ee = idx & 63;
    float v = sR[idx];
    jp[(blk * 64 + ee) * 72 + rt] = v;
    part = fmaf(v, v, part);
  }
  #pragma unroll
  for (int off = 32; off > 0; off >>= 1) part += __shfl_down(part, off, 64);
  if ((tid & 63) == 0) atomicAdd(&sRed[0], part);
  __syncthreads();
  if (tid == 0) atomicAdd(ws_sum, sRed[0]);
}

// ---------------------------------------------------------------------
// kl_kernel: one thread per element (unchanged from R3/R4 PASS).
__global__ __launch_bounds__(256) void kl_kernel(
    const float* __restrict__ zin, const float* __restrict__ jpin,
    const float* __restrict__ Wsym, const float* __restrict__ lvd,
    const float* __restrict__ ws_sum, float* __restrict__ out_kl) {
  int elem = blockIdx.x * 256 + threadIdx.x;
  float z[12];
  #pragma unroll
  for (int i = 0; i < 12; ++i) z[i] = zin[elem * 12 + i];
  float scale = 1.0f / sqrtf(ws_sum[0]);
  float Jp[6][12];
  #pragma unroll
  for (int n = 0; n < 6; ++n)
    #pragma unroll
    for (int j = 0; j < 12; ++j)
      Jp[n][j] = jpin[elem * 72 + n * 12 + j] * scale;

  float Sq[78];
  #pragma unroll
  for (int i = 0; i < 78; ++i) Sq[i] = 0.f;
  float tq = 0.f, tpq = 0.f;

  for (int m = 0; m < NBASE; ++m) {
    const float* Wm = Wsym + m * 144;
    float jq[12];
    #pragma unroll
    for (int j = 0; j < 12; ++j) {
      float acc = 0.f;
      #pragma unroll
      for (int i = 0; i < 12; ++i)
        acc = fmaf(Wm[j * 12 + i] - Wm[i * 12 + j], z[i], acc);
      jq[j] = acc;
    }
    #pragma unroll
    for (int i = 0; i < 12; ++i) {
      tq = fmaf(jq[i], jq[i], tq);
      #pragma unroll
      for (int j = 0; j <= i; ++j)
        Sq[i * (i + 1) / 2 + j] = fmaf(jq[i], jq[j], Sq[i * (i + 1) / 2 + j]);
    }
    #pragma unroll
    for (int n = 0; n < 6; ++n) {
      float d = 0.f;
      #pragma unroll
      for (int j = 0; j < 12; ++j) d = fmaf(Jp[n][j], jq[j], d);
      tpq = fmaf(d, d, tpq);
    }
  }

  float Dv[12], Db[12];
  #pragma unroll
  for (int j = 0; j < 12; ++j) Dv[j] = expf(-lvd[j]);

  float mh = 0.f;
  #pragma unroll
  for (int i = 0; i < 12; ++i) mh += Sq[i * (i + 1) / 2 + i] + Dv[i];
  float norm_H = fmaxf(mh * (1.f / 12.f), 1e-6f);
  #pragma unroll
  for (int i = 0; i < 12; ++i) Sq[i * (i + 1) / 2 + i] += Dv[i] + 1e-3f * norm_H;
  float sumDb = 0.f;
  #pragma unroll
  for (int j = 0; j < 12; ++j) { Db[j] = Dv[j] + 1e-3f * norm_H; sumDb += Db[j]; }

  float M[21];
  #pragma unroll
  for (int n = 0; n < 6; ++n)
    #pragma unroll
    for (int mm = 0; mm <= n; ++mm) {
      float acc = 0.f;
      #pragma unroll
      for (int j = 0; j < 12; ++j) acc = fmaf(Jp[n][j], Jp[mm][j], acc);
      M[n * (n + 1) / 2 + mm] = acc;
    }
  float md = 0.f;
  #pragma unroll
  for (int i = 0; i < 6; ++i) md += M[i * (i + 1) / 2 + i];
  float norm_M = fmaxf(md * (1.f / 6.f) + EPSP, 1e-6f);
  #pragma unroll
  for (int i = 0; i < 6; ++i) M[i * (i + 1) / 2 + i] += EPSP + 1e-3f * norm_M;

  float trace_p = 0.f;
  #pragma unroll
  for (int n = 0; n < 6; ++n)
    #pragma unroll
    for (int j = 0; j < 12; ++j)
      trace_p = fmaf(Jp[n][j] * Jp[n][j], Db[j], trace_p);

  float trace = (EPSP + 1e-3f * norm_M) * (sumDb + tq) + trace_p + tpq;

  float ldM = 0.f;
  #pragma unroll
  for (int jc = 0; jc < 6; ++jc) {
    float d = M[jc * (jc + 1) / 2 + jc];
    #pragma unroll
    for (int k = 0; k < jc; ++k) d -= M[jc * (jc + 1) / 2 + k] * M[jc * (jc + 1) / 2 + k];
    d = sqrtf(d);
    ldM += logf(d);
    float di = 1.f / d;
    M[jc * (jc + 1) / 2 + jc] = d;
    #pragma unroll
    for (int i2 = jc + 1; i2 < 6; ++i2) {
      float v = M[i2 * (i2 + 1) / 2 + jc];
      #pragma unroll
      for (int k = 0; k < jc; ++k) v -= M[i2 * (i2 + 1) / 2 + k] * M[jc * (jc + 1) / 2 + k];
      M[i2 * (i2 + 1) / 2 + jc] = v * di;
    }
  }

  float ldH = 0.f;
  #pragma unroll
  for (int jc = 0; jc < 12; ++jc) {
    float d = Sq[jc * (jc + 1) / 2 + jc];
    #pragma unroll
    for (int k = 0; k < jc; ++k) d -= Sq[jc * (jc + 1) / 2 + k] * Sq[jc * (jc + 1) / 2 + k];
    d = sqrtf(d);
    ldH += logf(d);
    float di = 1.f / d;
    Sq[jc * (jc + 1) / 2 + jc] = d;
    #pragma unroll
    for (int i2 = jc + 1; i2 < 12; ++i2) {
      float v = Sq[i2 * (i2 + 1) / 2 + jc];
      #pragma unroll
      for (int k = 0; k < jc; ++k) v -= Sq[i2 * (i2 + 1) / 2 + k] * Sq[jc * (jc + 1) / 2 + k];
      Sq[i2 * (i2 + 1) / 2 + jc] = v * di;
    }
  }

  float logdet_p = 2.f * ldM + 6.f * logf(EPSP);
  float logdet_q = 2.f * ldH;
  out_kl[elem] = 0.5f * (trace - (logdet_p + logdet_q) - 12.f);
}

// ---------------------------------------------------------------------
extern "C" void kernel_launch(void* const* d_in, const int* in_sizes, int n_in,
                              void* d_out, int out_size, void* d_ws, size_t ws_size,
                              hipStream_t stream) {
  (void)in_sizes; (void)n_in; (void)out_size; (void)ws_size;
  float* y    = (float*)d_in[0];   // consumed, then overwritten with z
  float* Jp   = (float*)d_in[1];   // consumed, then overwritten with pullback Jp
  const float* W1   = (const float*)d_in[2];
  const float* b1   = (const float*)d_in[3];
  const float* W2   = (const float*)d_in[4];
  const float* b2   = (const float*)d_in[5];
  const float* W3   = (const float*)d_in[6];
  const float* b3   = (const float*)d_in[7];
  const float* Wsym = (const float*)d_in[8];
  const float* lvd  = (const float*)d_in[9];
  float* out = (float*)d_out;      // fp32: [log_prob (B), kl (B)]

  float* ws_sum = (float*)d_ws;
  unsigned short* w2b = (unsigned short*)((char*)d_ws + 256);
  unsigned short* w2t = (unsigned short*)((char*)d_ws + 256 +
                                          NLAYER * HID * HID * 2);
  hipMemsetAsync(d_ws, 0, 4, stream);

  hipFuncSetAttribute((const void*)flow_kernel,
                      hipFuncAttributeMaxDynamicSharedMemorySize, SMEM_BYTES);

  prep_kernel<<<3456, 256, 0, stream>>>(W2, w2b, w2t);
  flow_kernel<<<256, 512, SMEM_BYTES, stream>>>(
      y, Jp, W1, b1, b2, W3, b3, w2b, w2t, ws_sum, out);
  kl_kernel<<<64, 256, 0, stream>>>(y, Jp, Wsym, lvd, ws_sum, out + BTOT);
}